// Round 3
// baseline (642.768 us; speedup 1.0000x reference)
//
#include <hip/hip_runtime.h>
#include <hip/hip_bf16.h>

// SubjectLayers: out[b,d] = sum_c x[b,c] * W[idx[b],c,d] + bias[idx[b],d]
// B=512, C=D=1024, 32 subjects, fp32.
//
// R2 lesson: compiler serialized W loads (VGPR=32 proves no batching; L3-warm
// replay same 96us => latency-bound). R3: inline-asm global_load_dwordx4 with
// counted vmcnt(4) double-buffer (4+4 in flight per wave), x rows via uniform
// s_load (readfirstlane'd pointers), no LDS, no barriers, CSEGS=8 for TLP.

typedef float f4v __attribute__((ext_vector_type(4)));

#define N_SUBJ 32
#define B_ROWS 512
#define IN_CH_K 1024
#define OUT_CH_K 1024
#define ROWS_PER_CHUNK 16
#define MAX_CHUNKS 64          // sum ceil(n_s/16) <= 62
#define CSEGS 8
#define CSEG 128               // IN_CH_K / CSEGS
#define DTILES 4
#define DTILE 256              // OUT_CH_K / DTILES

// d_ws layout:
//   int32 [0]                n_chunks
//   int32 [1 .. 1+3*64)      chunk entries {subject, start, cnt}
//   int32 [256 .. 768)       perm (row indices grouped by subject)
//   float [1024 ...)         partials: CSEGS x 512 x 1024 floats (16 MB)
#define ENT_OFF 1
#define PERM_OFF 256
#define PART_OFF_F 1024
#define PART_FLOATS (CSEGS * B_ROWS * OUT_CH_K)
#define WS_NEED_BYTES (4096 + (size_t)PART_FLOATS * 4)

__global__ __launch_bounds__(512) void build_groups(
    const int* __restrict__ idx, int* __restrict__ ws)
{
    __shared__ int counts[N_SUBJ];
    __shared__ int offs[N_SUBJ];
    __shared__ int cursor[N_SUBJ];
    const int t = threadIdx.x;
    if (t < N_SUBJ) counts[t] = 0;
    __syncthreads();
    const int s = idx[t] & (N_SUBJ - 1);
    atomicAdd(&counts[s], 1);
    __syncthreads();
    if (t == 0) {
        int acc = 0, nch = 0;
        for (int i = 0; i < N_SUBJ; ++i) {
            offs[i] = acc;
            cursor[i] = acc;
            acc += counts[i];
        }
        for (int i = 0; i < N_SUBJ; ++i) {
            for (int st = 0; st < counts[i]; st += ROWS_PER_CHUNK) {
                int c = counts[i] - st;
                if (c > ROWS_PER_CHUNK) c = ROWS_PER_CHUNK;
                ws[ENT_OFF + nch * 3 + 0] = i;
                ws[ENT_OFF + nch * 3 + 1] = offs[i] + st;
                ws[ENT_OFF + nch * 3 + 2] = c;
                ++nch;
            }
        }
        ws[0] = nch;
    }
    __syncthreads();
    const int pos = atomicAdd(&cursor[s], 1);
    ws[PERM_OFF + pos] = t;
}

__global__ __launch_bounds__(256) void init_bias(
    const int* __restrict__ idx, const float* __restrict__ bias,
    float* __restrict__ out)
{
    const int b = blockIdx.x;
    const int s = idx[b];
    const int d = threadIdx.x * 4;
    *(float4*)&out[(size_t)b * OUT_CH_K + d] =
        *(const float4*)&bias[(size_t)s * OUT_CH_K + d];
}

#define GLOAD(dst, ptr) \
    asm volatile("global_load_dwordx4 %0, %1, off" \
                 : "=v"(dst) : "v"(ptr) : "memory")
#define WAIT_VM(n) do { \
    asm volatile("s_waitcnt vmcnt(" #n ")" ::: "memory"); \
    __builtin_amdgcn_sched_barrier(0); } while (0)
#define FMA4(acc, w0, w1, w2, w3, xv) \
    acc += w0 * xv.x; acc += w1 * xv.y; acc += w2 * xv.z; acc += w3 * xv.w;

// grid: (chunk, cseg, dtile); block 256 = 4 waves; wave owns 4 rows of the
// chunk, lane owns 4 consecutive d. W streamed with 4+4 loads in flight.
template<bool ATOMIC>
__global__ __launch_bounds__(256) void subject_gemm(
    const float* __restrict__ x, const float* __restrict__ W,
    const int* __restrict__ ws, float* __restrict__ ws_part,
    float* __restrict__ out)
{
    const int chunk = blockIdx.x;
    const int nch = __builtin_amdgcn_readfirstlane(ws[0]);
    if (chunk >= nch) return;
    const int s     = __builtin_amdgcn_readfirstlane(ws[ENT_OFF + chunk * 3 + 0]);
    const int start = __builtin_amdgcn_readfirstlane(ws[ENT_OFF + chunk * 3 + 1]);
    const int cnt   = __builtin_amdgcn_readfirstlane(ws[ENT_OFF + chunk * 3 + 2]);
    const int cbase = blockIdx.y * CSEG;
    const int dbase = blockIdx.z * DTILE;

    const int t     = threadIdx.x;
    const int lane  = t & 63;
    const int wave  = t >> 6;
    const int rbase = wave * 4;
    if (rbase >= cnt) return;          // idle wave: exit (no barriers anywhere)
    const int nr = cnt - rbase;        // 1..4 valid rows for this wave

    const int r0 = __builtin_amdgcn_readfirstlane(ws[PERM_OFF + start + rbase + 0]);
    const int r1 = (nr > 1) ? __builtin_amdgcn_readfirstlane(ws[PERM_OFF + start + rbase + 1]) : r0;
    const int r2 = (nr > 2) ? __builtin_amdgcn_readfirstlane(ws[PERM_OFF + start + rbase + 2]) : r0;
    const int r3 = (nr > 3) ? __builtin_amdgcn_readfirstlane(ws[PERM_OFF + start + rbase + 3]) : r0;

    const float* xr0 = x + (size_t)r0 * IN_CH_K + cbase;
    const float* xr1 = x + (size_t)r1 * IN_CH_K + cbase;
    const float* xr2 = x + (size_t)r2 * IN_CH_K + cbase;
    const float* xr3 = x + (size_t)r3 * IN_CH_K + cbase;

    const int d = dbase + lane * 4;
    const float* wp = W + (size_t)s * IN_CH_K * OUT_CH_K
                        + (size_t)cbase * OUT_CH_K + d;

    f4v acc0 = {0.f, 0.f, 0.f, 0.f};
    f4v acc1 = {0.f, 0.f, 0.f, 0.f};
    f4v acc2 = {0.f, 0.f, 0.f, 0.f};
    f4v acc3 = {0.f, 0.f, 0.f, 0.f};
    f4v wa0, wa1, wa2, wa3, wb0, wb1, wb2, wb3;

    WAIT_VM(0);  // drain any prologue vmem so vmcnt counts are deterministic

    GLOAD(wa0, wp + 0 * OUT_CH_K);
    GLOAD(wa1, wp + 1 * OUT_CH_K);
    GLOAD(wa2, wp + 2 * OUT_CH_K);
    GLOAD(wa3, wp + 3 * OUT_CH_K);

    #pragma unroll
    for (int cb = 0; cb < CSEG; cb += 8) {
        {   // issue B batch: c = cb+4 .. cb+7
            const float* wq = wp + (size_t)(cb + 4) * OUT_CH_K;
            GLOAD(wb0, wq + 0 * OUT_CH_K);
            GLOAD(wb1, wq + 1 * OUT_CH_K);
            GLOAD(wb2, wq + 2 * OUT_CH_K);
            GLOAD(wb3, wq + 3 * OUT_CH_K);
        }
        const float4 xa0 = *(const float4*)(xr0 + cb);
        const float4 xa1 = *(const float4*)(xr1 + cb);
        const float4 xa2 = *(const float4*)(xr2 + cb);
        const float4 xa3 = *(const float4*)(xr3 + cb);
        WAIT_VM(4);                    // A batch landed, B still in flight
        FMA4(acc0, wa0, wa1, wa2, wa3, xa0)
        FMA4(acc1, wa0, wa1, wa2, wa3, xa1)
        FMA4(acc2, wa0, wa1, wa2, wa3, xa2)
        FMA4(acc3, wa0, wa1, wa2, wa3, xa3)

        const float4 xb0 = *(const float4*)(xr0 + cb + 4);
        const float4 xb1 = *(const float4*)(xr1 + cb + 4);
        const float4 xb2 = *(const float4*)(xr2 + cb + 4);
        const float4 xb3 = *(const float4*)(xr3 + cb + 4);
        if (cb + 8 < CSEG) {           // issue next A batch, then wait B
            const float* wr = wp + (size_t)(cb + 8) * OUT_CH_K;
            GLOAD(wa0, wr + 0 * OUT_CH_K);
            GLOAD(wa1, wr + 1 * OUT_CH_K);
            GLOAD(wa2, wr + 2 * OUT_CH_K);
            GLOAD(wa3, wr + 3 * OUT_CH_K);
            WAIT_VM(4);
        } else {
            WAIT_VM(0);
        }
        FMA4(acc0, wb0, wb1, wb2, wb3, xb0)
        FMA4(acc1, wb0, wb1, wb2, wb3, xb1)
        FMA4(acc2, wb0, wb1, wb2, wb3, xb2)
        FMA4(acc3, wb0, wb1, wb2, wb3, xb3)
    }

    if (ATOMIC) {
        float* o0 = &out[(size_t)r0 * OUT_CH_K + d];
        atomicAdd(o0 + 0, acc0.x); atomicAdd(o0 + 1, acc0.y);
        atomicAdd(o0 + 2, acc0.z); atomicAdd(o0 + 3, acc0.w);
        if (nr > 1) {
            float* o = &out[(size_t)r1 * OUT_CH_K + d];
            atomicAdd(o + 0, acc1.x); atomicAdd(o + 1, acc1.y);
            atomicAdd(o + 2, acc1.z); atomicAdd(o + 3, acc1.w);
        }
        if (nr > 2) {
            float* o = &out[(size_t)r2 * OUT_CH_K + d];
            atomicAdd(o + 0, acc2.x); atomicAdd(o + 1, acc2.y);
            atomicAdd(o + 2, acc2.z); atomicAdd(o + 3, acc2.w);
        }
        if (nr > 3) {
            float* o = &out[(size_t)r3 * OUT_CH_K + d];
            atomicAdd(o + 0, acc3.x); atomicAdd(o + 1, acc3.y);
            atomicAdd(o + 2, acc3.z); atomicAdd(o + 3, acc3.w);
        }
    } else {
        float* pb = ws_part + (size_t)blockIdx.y * B_ROWS * OUT_CH_K + d;
        *(f4v*)(pb + (size_t)r0 * OUT_CH_K) = acc0;
        if (nr > 1) *(f4v*)(pb + (size_t)r1 * OUT_CH_K) = acc1;
        if (nr > 2) *(f4v*)(pb + (size_t)r2 * OUT_CH_K) = acc2;
        if (nr > 3) *(f4v*)(pb + (size_t)r3 * OUT_CH_K) = acc3;
    }
}

// out[b,d] = bias[idx[b],d] + sum_k part[k][b][d]
__global__ __launch_bounds__(256) void reduce_parts(
    const int* __restrict__ idx, const float* __restrict__ bias,
    const float* __restrict__ part, float* __restrict__ out)
{
    const int b = blockIdx.x;
    const int s = idx[b];
    const int d = threadIdx.x * 4;
    float4 a = *(const float4*)&bias[(size_t)s * OUT_CH_K + d];
    #pragma unroll
    for (int k = 0; k < CSEGS; ++k) {
        const float4 p = *(const float4*)
            &part[((size_t)k * B_ROWS + b) * OUT_CH_K + d];
        a.x += p.x; a.y += p.y; a.z += p.z; a.w += p.w;
    }
    *(float4*)&out[(size_t)b * OUT_CH_K + d] = a;
}

extern "C" void kernel_launch(void* const* d_in, const int* in_sizes, int n_in,
                              void* d_out, int out_size, void* d_ws, size_t ws_size,
                              hipStream_t stream) {
    const float* x    = (const float*)d_in[0];
    const int*   idx  = (const int*)d_in[1];
    const float* W    = (const float*)d_in[2];
    const float* bias = (const float*)d_in[3];
    float* out = (float*)d_out;
    int* ws = (int*)d_ws;
    float* ws_part = (float*)ws + PART_OFF_F;

    build_groups<<<1, 512, 0, stream>>>(idx, ws);

    dim3 grid(MAX_CHUNKS, CSEGS, DTILES);  // (64,8,4) -> ~1500-2000 active blocks
    if (ws_size >= WS_NEED_BYTES) {
        subject_gemm<false><<<grid, 256, 0, stream>>>(x, W, ws, ws_part, out);
        reduce_parts<<<B_ROWS, 256, 0, stream>>>(idx, bias, ws_part, out);
    } else {
        init_bias<<<B_ROWS, 256, 0, stream>>>(idx, bias, out);
        subject_gemm<true><<<grid, 256, 0, stream>>>(x, W, ws, ws_part, out);
    }
}

// Round 4
// 244.452 us; speedup vs baseline: 2.6294x; 2.6294x over previous
//
#include <hip/hip_runtime.h>
#include <hip/hip_bf16.h>

// SubjectLayers: out[b,d] = sum_c x[b,c] * W[idx[b],c,d] + bias[idx[b],d]
// B=512, C=D=1024, 32 subjects, fp32. Memory-bound on W (~128 MB read once,
// floor ~25 us incl. partials).
//
// R2: compiler serialized W loads -> latency-bound at 96 us.
// R3: full unroll + asm batches blew VGPR to 256 -> spills (WRITE 338 MB),
//     occupancy ~5% -> 500 us.
// R4: x staged in LDS (loop has NO compiler vmem -> exact vmcnt counts),
//     rolled loop (#pragma unroll 1) with two named 4-deep asm load batches
//     (8 KB/wave in flight), peeled epilogue, launch_bounds(256,4) caps VGPR.

typedef float f4v __attribute__((ext_vector_type(4)));

#define N_SUBJ 32
#define B_ROWS 512
#define IN_CH_K 1024
#define OUT_CH_K 1024
#define ROWS_PER_CHUNK 16
#define MAX_CHUNKS 64          // sum ceil(n_s/16) <= 62
#define CSEGS 4
#define CSEG 256               // IN_CH_K / CSEGS
#define DTILES 4
#define DTILE 256              // OUT_CH_K / DTILES

// d_ws layout:
//   int32 [0]                n_chunks
//   int32 [1 .. 1+3*64)      chunk entries {subject, start, cnt}
//   int32 [256 .. 768)       perm (row indices grouped by subject)
//   float [1024 ...)         partials: CSEGS x 512 x 1024 floats (8 MB)
#define ENT_OFF 1
#define PERM_OFF 256
#define PART_OFF_F 1024
#define PART_FLOATS (CSEGS * B_ROWS * OUT_CH_K)
#define WS_NEED_BYTES (4096 + (size_t)PART_FLOATS * 4)

__global__ __launch_bounds__(512) void build_groups(
    const int* __restrict__ idx, int* __restrict__ ws)
{
    __shared__ int counts[N_SUBJ];
    __shared__ int offs[N_SUBJ];
    __shared__ int cursor[N_SUBJ];
    const int t = threadIdx.x;
    if (t < N_SUBJ) counts[t] = 0;
    __syncthreads();
    const int s = idx[t] & (N_SUBJ - 1);
    atomicAdd(&counts[s], 1);
    __syncthreads();
    if (t == 0) {
        int acc = 0, nch = 0;
        for (int i = 0; i < N_SUBJ; ++i) {
            offs[i] = acc;
            cursor[i] = acc;
            acc += counts[i];
        }
        for (int i = 0; i < N_SUBJ; ++i) {
            for (int st = 0; st < counts[i]; st += ROWS_PER_CHUNK) {
                int c = counts[i] - st;
                if (c > ROWS_PER_CHUNK) c = ROWS_PER_CHUNK;
                ws[ENT_OFF + nch * 3 + 0] = i;
                ws[ENT_OFF + nch * 3 + 1] = offs[i] + st;
                ws[ENT_OFF + nch * 3 + 2] = c;
                ++nch;
            }
        }
        ws[0] = nch;
    }
    __syncthreads();
    const int pos = atomicAdd(&cursor[s], 1);
    ws[PERM_OFF + pos] = t;
}

__global__ __launch_bounds__(256) void init_bias(
    const int* __restrict__ idx, const float* __restrict__ bias,
    float* __restrict__ out)
{
    const int b = blockIdx.x;
    const int s = idx[b];
    const int d = threadIdx.x * 4;
    *(float4*)&out[(size_t)b * OUT_CH_K + d] =
        *(const float4*)&bias[(size_t)s * OUT_CH_K + d];
}

#define GLOAD(dst, ptr) \
    asm volatile("global_load_dwordx4 %0, %1, off" : "=v"(dst) : "v"(ptr))
#define WAIT_VM(n) do { \
    asm volatile("s_waitcnt vmcnt(" #n ")" ::: "memory"); \
    __builtin_amdgcn_sched_barrier(0); } while (0)
#define FMA4(acc, w0, w1, w2, w3, xv) \
    acc += w0 * xv.x; acc += w1 * xv.y; acc += w2 * xv.z; acc += w3 * xv.w;

// grid: (chunk, cseg, dtile); block 256 = 4 waves; wave owns 4 chunk rows,
// lane owns 4 consecutive d. W streamed via asm dwordx4, 8 loads in flight.
template<bool ATOMIC>
__global__ __launch_bounds__(256, 4) void subject_gemm(
    const float* __restrict__ x, const float* __restrict__ W,
    const int* __restrict__ ws, float* __restrict__ ws_part,
    float* __restrict__ out)
{
    const int chunk = blockIdx.x;
    if (chunk >= ws[0]) return;
    const int s     = ws[ENT_OFF + chunk * 3 + 0];
    const int start = ws[ENT_OFF + chunk * 3 + 1];
    const int cnt   = ws[ENT_OFF + chunk * 3 + 2];
    const int cbase = blockIdx.y * CSEG;
    const int dbase = blockIdx.z * DTILE;

    __shared__ float xs[ROWS_PER_CHUNK][CSEG];
    __shared__ int rowidx[ROWS_PER_CHUNK];

    const int t = threadIdx.x;
    if (t < ROWS_PER_CHUNK)
        rowidx[t] = (t < cnt) ? ws[PERM_OFF + start + t] : -1;
    __syncthreads();

    // stage x tile (16 rows x 256 c), zero-fill invalid rows
    #pragma unroll
    for (int i = 0; i < ROWS_PER_CHUNK; ++i) {
        const int r = rowidx[i];
        xs[i][t] = (r >= 0) ? x[(size_t)r * IN_CH_K + cbase + t] : 0.0f;
    }
    __syncthreads();   // compiler drains vmcnt(0) here -> counts deterministic

    const int lane  = t & 63;
    const int wave  = t >> 6;
    const int rbase = wave * 4;
    if (rbase >= cnt) return;          // idle wave exits (no barriers below)
    const int nr = cnt - rbase;

    const int d = dbase + lane * 4;
    const float* wp = W + (size_t)s * (IN_CH_K * OUT_CH_K)
                        + (size_t)cbase * OUT_CH_K + d;

    f4v acc0 = {0.f, 0.f, 0.f, 0.f};
    f4v acc1 = {0.f, 0.f, 0.f, 0.f};
    f4v acc2 = {0.f, 0.f, 0.f, 0.f};
    f4v acc3 = {0.f, 0.f, 0.f, 0.f};
    f4v wa0, wa1, wa2, wa3, wb0, wb1, wb2, wb3;

    GLOAD(wa0, wp + 0 * OUT_CH_K);
    GLOAD(wa1, wp + 1 * OUT_CH_K);
    GLOAD(wa2, wp + 2 * OUT_CH_K);
    GLOAD(wa3, wp + 3 * OUT_CH_K);
    GLOAD(wb0, wp + 4 * OUT_CH_K);
    GLOAD(wb1, wp + 5 * OUT_CH_K);
    GLOAD(wb2, wp + 6 * OUT_CH_K);
    GLOAD(wb3, wp + 7 * OUT_CH_K);

    // steady state: 8 dwordx4 (8 KB/wave) outstanding; vmcnt(4) per half-batch
    #pragma unroll 1
    for (int cb = 0; cb < CSEG - 8; cb += 8) {
        const float4 xa0 = *(const float4*)&xs[rbase + 0][cb];
        const float4 xa1 = *(const float4*)&xs[rbase + 1][cb];
        const float4 xa2 = *(const float4*)&xs[rbase + 2][cb];
        const float4 xa3 = *(const float4*)&xs[rbase + 3][cb];
        WAIT_VM(4);                        // A batch landed, B in flight
        FMA4(acc0, wa0, wa1, wa2, wa3, xa0)
        FMA4(acc1, wa0, wa1, wa2, wa3, xa1)
        FMA4(acc2, wa0, wa1, wa2, wa3, xa2)
        FMA4(acc3, wa0, wa1, wa2, wa3, xa3)
        const float* wn = wp + (size_t)(cb + 8) * OUT_CH_K;
        GLOAD(wa0, wn + 0 * OUT_CH_K);     // next A: c = cb+8..cb+11
        GLOAD(wa1, wn + 1 * OUT_CH_K);
        GLOAD(wa2, wn + 2 * OUT_CH_K);
        GLOAD(wa3, wn + 3 * OUT_CH_K);

        const float4 xb0 = *(const float4*)&xs[rbase + 0][cb + 4];
        const float4 xb1 = *(const float4*)&xs[rbase + 1][cb + 4];
        const float4 xb2 = *(const float4*)&xs[rbase + 2][cb + 4];
        const float4 xb3 = *(const float4*)&xs[rbase + 3][cb + 4];
        WAIT_VM(4);                        // B landed, next-A in flight
        FMA4(acc0, wb0, wb1, wb2, wb3, xb0)
        FMA4(acc1, wb0, wb1, wb2, wb3, xb1)
        FMA4(acc2, wb0, wb1, wb2, wb3, xb2)
        FMA4(acc3, wb0, wb1, wb2, wb3, xb3)
        GLOAD(wb0, wn + 4 * OUT_CH_K);     // next B: c = cb+12..cb+15
        GLOAD(wb1, wn + 5 * OUT_CH_K);
        GLOAD(wb2, wn + 6 * OUT_CH_K);
        GLOAD(wb3, wn + 7 * OUT_CH_K);
    }
    {   // epilogue: cb = CSEG-8
        const int cb = CSEG - 8;
        const float4 xa0 = *(const float4*)&xs[rbase + 0][cb];
        const float4 xa1 = *(const float4*)&xs[rbase + 1][cb];
        const float4 xa2 = *(const float4*)&xs[rbase + 2][cb];
        const float4 xa3 = *(const float4*)&xs[rbase + 3][cb];
        WAIT_VM(4);
        FMA4(acc0, wa0, wa1, wa2, wa3, xa0)
        FMA4(acc1, wa0, wa1, wa2, wa3, xa1)
        FMA4(acc2, wa0, wa1, wa2, wa3, xa2)
        FMA4(acc3, wa0, wa1, wa2, wa3, xa3)
        const float4 xb0 = *(const float4*)&xs[rbase + 0][cb + 4];
        const float4 xb1 = *(const float4*)&xs[rbase + 1][cb + 4];
        const float4 xb2 = *(const float4*)&xs[rbase + 2][cb + 4];
        const float4 xb3 = *(const float4*)&xs[rbase + 3][cb + 4];
        WAIT_VM(0);
        FMA4(acc0, wb0, wb1, wb2, wb3, xb0)
        FMA4(acc1, wb0, wb1, wb2, wb3, xb1)
        FMA4(acc2, wb0, wb1, wb2, wb3, xb2)
        FMA4(acc3, wb0, wb1, wb2, wb3, xb3)
    }

    const int r0 = rowidx[rbase + 0];
    const int r1 = (nr > 1) ? rowidx[rbase + 1] : 0;
    const int r2 = (nr > 2) ? rowidx[rbase + 2] : 0;
    const int r3 = (nr > 3) ? rowidx[rbase + 3] : 0;

    if (ATOMIC) {
        float* o0 = &out[(size_t)r0 * OUT_CH_K + d];
        atomicAdd(o0 + 0, acc0.x); atomicAdd(o0 + 1, acc0.y);
        atomicAdd(o0 + 2, acc0.z); atomicAdd(o0 + 3, acc0.w);
        if (nr > 1) {
            float* o = &out[(size_t)r1 * OUT_CH_K + d];
            atomicAdd(o + 0, acc1.x); atomicAdd(o + 1, acc1.y);
            atomicAdd(o + 2, acc1.z); atomicAdd(o + 3, acc1.w);
        }
        if (nr > 2) {
            float* o = &out[(size_t)r2 * OUT_CH_K + d];
            atomicAdd(o + 0, acc2.x); atomicAdd(o + 1, acc2.y);
            atomicAdd(o + 2, acc2.z); atomicAdd(o + 3, acc2.w);
        }
        if (nr > 3) {
            float* o = &out[(size_t)r3 * OUT_CH_K + d];
            atomicAdd(o + 0, acc3.x); atomicAdd(o + 1, acc3.y);
            atomicAdd(o + 2, acc3.z); atomicAdd(o + 3, acc3.w);
        }
    } else {
        float* pb = ws_part + (size_t)blockIdx.y * (B_ROWS * OUT_CH_K) + d;
        *(f4v*)(pb + (size_t)r0 * OUT_CH_K) = acc0;
        if (nr > 1) *(f4v*)(pb + (size_t)r1 * OUT_CH_K) = acc1;
        if (nr > 2) *(f4v*)(pb + (size_t)r2 * OUT_CH_K) = acc2;
        if (nr > 3) *(f4v*)(pb + (size_t)r3 * OUT_CH_K) = acc3;
    }
}

// out[b,d] = bias[idx[b],d] + sum_k part[k][b][d]
__global__ __launch_bounds__(256) void reduce_parts(
    const int* __restrict__ idx, const float* __restrict__ bias,
    const float* __restrict__ part, float* __restrict__ out)
{
    const int b = blockIdx.x;
    const int s = idx[b];
    const int d = threadIdx.x * 4;
    float4 a = *(const float4*)&bias[(size_t)s * OUT_CH_K + d];
    #pragma unroll
    for (int k = 0; k < CSEGS; ++k) {
        const float4 p = *(const float4*)
            &part[((size_t)k * B_ROWS + b) * OUT_CH_K + d];
        a.x += p.x; a.y += p.y; a.z += p.z; a.w += p.w;
    }
    *(float4*)&out[(size_t)b * OUT_CH_K + d] = a;
}

extern "C" void kernel_launch(void* const* d_in, const int* in_sizes, int n_in,
                              void* d_out, int out_size, void* d_ws, size_t ws_size,
                              hipStream_t stream) {
    const float* x    = (const float*)d_in[0];
    const int*   idx  = (const int*)d_in[1];
    const float* W    = (const float*)d_in[2];
    const float* bias = (const float*)d_in[3];
    float* out = (float*)d_out;
    int* ws = (int*)d_ws;
    float* ws_part = (float*)ws + PART_OFF_F;

    build_groups<<<1, 512, 0, stream>>>(idx, ws);

    dim3 grid(MAX_CHUNKS, CSEGS, DTILES);  // (64,4,4) -> ~750-1000 active blocks
    if (ws_size >= WS_NEED_BYTES) {
        subject_gemm<false><<<grid, 256, 0, stream>>>(x, W, ws, ws_part, out);
        reduce_parts<<<B_ROWS, 256, 0, stream>>>(idx, bias, ws_part, out);
    } else {
        init_bias<<<B_ROWS, 256, 0, stream>>>(idx, bias, out);
        subject_gemm<true><<<grid, 256, 0, stream>>>(x, W, ws, ws_part, out);
    }
}

// Round 5
// 226.285 us; speedup vs baseline: 2.8405x; 1.0803x over previous
//
#include <hip/hip_runtime.h>
#include <hip/hip_bf16.h>

// SubjectLayers: out[b,d] = sum_c x[b,c] * W[idx[b],c,d] + bias[idx[b],d]
// B=512, C=D=1024, 32 subjects, fp32.
//
// R4 analysis: waves split ROWS and shared W -> 4x redundant VMEM issue
// (563 MB issued = 6.2 TB/s = the 10 B/cy/CU VMEM ceiling). R5: waves split
// the C dimension -> disjoint W loads (issued == HBM ~110 MB). Each wave
// accumulates all 16 rows (16 f4v acc), x via uniform LDS broadcasts from a
// transposed padded tile, cross-wave combine via phased LDS reduction.

typedef float f4v __attribute__((ext_vector_type(4)));

#define N_SUBJ 32
#define B_ROWS 512
#define IN_CH_K 1024
#define OUT_CH_K 1024
#define ROWS_PER_CHUNK 16
#define MAX_CHUNKS 64          // sum ceil(n_s/16) <= 62
#define CSEGS 4
#define CSEG 256               // block c-tile; each of 4 waves owns 64 rows
#define WSLICE 64              // CSEG / 4 waves
#define DTILES 4
#define DTILE 256
#define XPAD 20                // xst row stride (floats): 16B-aligned, 8-way-max bank spread

// d_ws layout:
//   int32 [0]                n_chunks
//   int32 [1 .. 1+3*64)      chunk entries {subject, start, cnt}
//   int32 [256 .. 768)       perm (row indices grouped by subject)
//   float [1024 ...)         partials: CSEGS x 512 x 1024 floats (8 MB)
#define ENT_OFF 1
#define PERM_OFF 256
#define PART_OFF_F 1024
#define PART_FLOATS (CSEGS * B_ROWS * OUT_CH_K)
#define WS_NEED_BYTES (4096 + (size_t)PART_FLOATS * 4)

__global__ __launch_bounds__(512) void build_groups(
    const int* __restrict__ idx, int* __restrict__ ws)
{
    __shared__ int counts[N_SUBJ];
    __shared__ int offs[N_SUBJ];
    __shared__ int cursor[N_SUBJ];
    const int t = threadIdx.x;
    if (t < N_SUBJ) counts[t] = 0;
    __syncthreads();
    const int s = idx[t] & (N_SUBJ - 1);
    atomicAdd(&counts[s], 1);
    __syncthreads();
    if (t == 0) {
        int acc = 0, nch = 0;
        for (int i = 0; i < N_SUBJ; ++i) {
            offs[i] = acc;
            cursor[i] = acc;
            acc += counts[i];
        }
        for (int i = 0; i < N_SUBJ; ++i) {
            for (int st = 0; st < counts[i]; st += ROWS_PER_CHUNK) {
                int c = counts[i] - st;
                if (c > ROWS_PER_CHUNK) c = ROWS_PER_CHUNK;
                ws[ENT_OFF + nch * 3 + 0] = i;
                ws[ENT_OFF + nch * 3 + 1] = offs[i] + st;
                ws[ENT_OFF + nch * 3 + 2] = c;
                ++nch;
            }
        }
        ws[0] = nch;
    }
    __syncthreads();
    const int pos = atomicAdd(&cursor[s], 1);
    ws[PERM_OFF + pos] = t;
}

__global__ __launch_bounds__(256) void init_bias(
    const int* __restrict__ idx, const float* __restrict__ bias,
    float* __restrict__ out)
{
    const int b = blockIdx.x;
    const int s = idx[b];
    const int d = threadIdx.x * 4;
    *(float4*)&out[(size_t)b * OUT_CH_K + d] =
        *(const float4*)&bias[(size_t)s * OUT_CH_K + d];
}

#define GLOAD(dst, ptr) \
    asm volatile("global_load_dwordx4 %0, %1, off" : "=v"(dst) : "v"(ptr))
#define WAIT_VM(n) do { \
    asm volatile("s_waitcnt vmcnt(" #n ")" ::: "memory"); \
    __builtin_amdgcn_sched_barrier(0); } while (0)

// One c-row: w4 = W[c][d:d+4] (per lane), x broadcast from xst[c][0..15]
#define CSTEP(wreg, cidx) { \
    const float4 x0 = ((const float4*)&xst[cidx][0])[0]; \
    const float4 x1 = ((const float4*)&xst[cidx][0])[1]; \
    const float4 x2 = ((const float4*)&xst[cidx][0])[2]; \
    const float4 x3 = ((const float4*)&xst[cidx][0])[3]; \
    acc[ 0] += wreg * x0.x;  acc[ 1] += wreg * x0.y; \
    acc[ 2] += wreg * x0.z;  acc[ 3] += wreg * x0.w; \
    acc[ 4] += wreg * x1.x;  acc[ 5] += wreg * x1.y; \
    acc[ 6] += wreg * x1.z;  acc[ 7] += wreg * x1.w; \
    acc[ 8] += wreg * x2.x;  acc[ 9] += wreg * x2.y; \
    acc[10] += wreg * x2.z;  acc[11] += wreg * x2.w; \
    acc[12] += wreg * x3.x;  acc[13] += wreg * x3.y; \
    acc[14] += wreg * x3.z;  acc[15] += wreg * x3.w; }

// grid: (chunk, cseg, dtile); block 256 = 4 waves. Wave w streams c-rows
// [cbase + w*64, +64) x full DTILE (disjoint W!), accumulating all 16 rows.
template<bool ATOMIC>
__global__ __launch_bounds__(256, 3) void subject_gemm(
    const float* __restrict__ x, const float* __restrict__ W,
    const int* __restrict__ ws, float* __restrict__ ws_part,
    float* __restrict__ out)
{
    const int chunk = blockIdx.x;
    if (chunk >= ws[0]) return;                  // uniform block exit
    const int s     = ws[ENT_OFF + chunk * 3 + 0];
    const int start = ws[ENT_OFF + chunk * 3 + 1];
    const int cnt   = ws[ENT_OFF + chunk * 3 + 2];
    const int cbase = blockIdx.y * CSEG;
    const int dbase = blockIdx.z * DTILE;

    __shared__ float xst[CSEG][XPAD];            // transposed x tile: [c][row]
    __shared__ int rowidx[ROWS_PER_CHUNK];

    const int t = threadIdx.x;
    if (t < ROWS_PER_CHUNK)
        rowidx[t] = (t < cnt) ? ws[PERM_OFF + start + t] : -1;
    __syncthreads();

    #pragma unroll
    for (int r = 0; r < ROWS_PER_CHUNK; ++r) {
        const int row = rowidx[r];
        xst[t][r] = (row >= 0) ? x[(size_t)row * IN_CH_K + cbase + t] : 0.0f;
    }
    __syncthreads();   // drains vmcnt(0) -> asm counts below are deterministic

    const int lane = t & 63;
    const int wave = t >> 6;
    const int cs   = wave * WSLICE;              // this wave's c-slice in tile
    const int d    = dbase + lane * 4;
    const float* wp = W + (size_t)s * (IN_CH_K * OUT_CH_K)
                        + (size_t)(cbase + cs) * OUT_CH_K + d;

    f4v acc[16];
    #pragma unroll
    for (int r = 0; r < 16; ++r) acc[r] = (f4v){0.f, 0.f, 0.f, 0.f};
    f4v wa0, wa1, wa2, wa3, wb0, wb1, wb2, wb3;

    GLOAD(wa0, wp + 0 * OUT_CH_K);
    GLOAD(wa1, wp + 1 * OUT_CH_K);
    GLOAD(wa2, wp + 2 * OUT_CH_K);
    GLOAD(wa3, wp + 3 * OUT_CH_K);
    GLOAD(wb0, wp + 4 * OUT_CH_K);
    GLOAD(wb1, wp + 5 * OUT_CH_K);
    GLOAD(wb2, wp + 6 * OUT_CH_K);
    GLOAD(wb3, wp + 7 * OUT_CH_K);

    #pragma unroll 1
    for (int cb = 0; cb < WSLICE - 8; cb += 8) {
        WAIT_VM(4);                              // A landed, B in flight
        CSTEP(wa0, cs + cb + 0)
        CSTEP(wa1, cs + cb + 1)
        CSTEP(wa2, cs + cb + 2)
        CSTEP(wa3, cs + cb + 3)
        const float* wn = wp + (size_t)(cb + 8) * OUT_CH_K;
        GLOAD(wa0, wn + 0 * OUT_CH_K);
        GLOAD(wa1, wn + 1 * OUT_CH_K);
        GLOAD(wa2, wn + 2 * OUT_CH_K);
        GLOAD(wa3, wn + 3 * OUT_CH_K);
        WAIT_VM(4);                              // B landed, next-A in flight
        CSTEP(wb0, cs + cb + 4)
        CSTEP(wb1, cs + cb + 5)
        CSTEP(wb2, cs + cb + 6)
        CSTEP(wb3, cs + cb + 7)
        GLOAD(wb0, wn + 4 * OUT_CH_K);
        GLOAD(wb1, wn + 5 * OUT_CH_K);
        GLOAD(wb2, wn + 6 * OUT_CH_K);
        GLOAD(wb3, wn + 7 * OUT_CH_K);
    }
    {   // epilogue: cb = WSLICE-8
        const int cb = WSLICE - 8;
        WAIT_VM(4);
        CSTEP(wa0, cs + cb + 0)
        CSTEP(wa1, cs + cb + 1)
        CSTEP(wa2, cs + cb + 2)
        CSTEP(wa3, cs + cb + 3)
        WAIT_VM(0);
        CSTEP(wb0, cs + cb + 4)
        CSTEP(wb1, cs + cb + 5)
        CSTEP(wb2, cs + cb + 6)
        CSTEP(wb3, cs + cb + 7)
    }

    // ---- cross-wave reduction through LDS (reuse xst memory: 16KB<=20KB) ----
    __syncthreads();                             // xst dead after this point
    float (*obuf)[DTILE] = (float(*)[DTILE])&xst[0][0];
    if (wave == 0) {
        #pragma unroll
        for (int r = 0; r < 16; ++r)
            *(f4v*)&obuf[r][lane * 4] = acc[r];
    }
    __syncthreads();
    #pragma unroll
    for (int w = 1; w < 4; ++w) {
        if (wave == w) {
            #pragma unroll
            for (int r = 0; r < 16; ++r) {
                f4v v = *(const f4v*)&obuf[r][lane * 4];
                *(f4v*)&obuf[r][lane * 4] = v + acc[r];
            }
        }
        __syncthreads();
    }

    // write: wave w handles rows 4w..4w+3
    #pragma unroll
    for (int i = 0; i < 4; ++i) {
        const int r = wave * 4 + i;
        const int row = rowidx[r];
        if (row >= 0) {
            const f4v v = *(const f4v*)&obuf[r][lane * 4];
            if (ATOMIC) {
                float* o = &out[(size_t)row * OUT_CH_K + d];
                atomicAdd(o + 0, v.x); atomicAdd(o + 1, v.y);
                atomicAdd(o + 2, v.z); atomicAdd(o + 3, v.w);
            } else {
                *(f4v*)&ws_part[((size_t)blockIdx.y * B_ROWS + row)
                                * OUT_CH_K + d] = v;
            }
        }
    }
}

// out[b,d] = bias[idx[b],d] + sum_k part[k][b][d]
__global__ __launch_bounds__(256) void reduce_parts(
    const int* __restrict__ idx, const float* __restrict__ bias,
    const float* __restrict__ part, float* __restrict__ out)
{
    const int b = blockIdx.x;
    const int s = idx[b];
    const int d = threadIdx.x * 4;
    float4 a = *(const float4*)&bias[(size_t)s * OUT_CH_K + d];
    #pragma unroll
    for (int k = 0; k < CSEGS; ++k) {
        const float4 p = *(const float4*)
            &part[((size_t)k * B_ROWS + b) * OUT_CH_K + d];
        a.x += p.x; a.y += p.y; a.z += p.z; a.w += p.w;
    }
    *(float4*)&out[(size_t)b * OUT_CH_K + d] = a;
}

extern "C" void kernel_launch(void* const* d_in, const int* in_sizes, int n_in,
                              void* d_out, int out_size, void* d_ws, size_t ws_size,
                              hipStream_t stream) {
    const float* x    = (const float*)d_in[0];
    const int*   idx  = (const int*)d_in[1];
    const float* W    = (const float*)d_in[2];
    const float* bias = (const float*)d_in[3];
    float* out = (float*)d_out;
    int* ws = (int*)d_ws;
    float* ws_part = (float*)ws + PART_OFF_F;

    build_groups<<<1, 512, 0, stream>>>(idx, ws);

    dim3 grid(MAX_CHUNKS, CSEGS, DTILES);  // (64,4,4), ~992 active blocks x 4 waves
    if (ws_size >= WS_NEED_BYTES) {
        subject_gemm<false><<<grid, 256, 0, stream>>>(x, W, ws, ws_part, out);
        reduce_parts<<<B_ROWS, 256, 0, stream>>>(idx, bias, ws_part, out);
    } else {
        init_bias<<<B_ROWS, 256, 0, stream>>>(idx, bias, out);
        subject_gemm<true><<<grid, 256, 0, stream>>>(x, W, ws, ws_part, out);
    }
}